// Round 2
// baseline (8794.680 us; speedup 1.0000x reference)
//
#include <hip/hip_runtime.h>
#include <hip/hip_bf16.h>

// ---------------------------------------------------------------------------
// BottleneckVQa: enc(conv5x5 s2 -> gelu -> conv5x5 s2 -> gelu -> conv2x2) ->
// VQ argmin over 24 codes -> dec(conv2x2 p1 -> gelu -> conv2x2 -> gelu ->
// conv2x2 p1). All inputs/outputs fp32 (reference dtypes). Encoder
// intermediates fp32 (argmin stability); decoder intermediates bf16 in ws.
// ---------------------------------------------------------------------------

#define DEV_INLINE __device__ __forceinline__

DEV_INLINE float gelu_exact(float v) {
    return 0.5f * v * (1.0f + erff(v * 0.70710678118654752440f));
}

// ---- conv1: [32,3,256,256] -> [32,64,128,128], k5 s2 p2, + gelu, fp32 out ----
__global__ void conv1_k(const float* __restrict__ x,
                        const float* __restrict__ w,   // [64,3,5,5]
                        float* __restrict__ z1) {
    __shared__ float wl[300];                 // [c*25+tap][j], 4 oc per block
    const int oc0 = blockIdx.y * 4;
    for (int i = threadIdx.x; i < 300; i += 256) {
        int j = i & 3, r = i >> 2;
        wl[i] = w[(oc0 + j) * 75 + r];
    }
    __syncthreads();
    const int s = blockIdx.x * 256 + threadIdx.x;   // < 16384
    const int n = blockIdx.z;
    const int oy = s >> 7, ox = s & 127;
    const float4* wv = (const float4*)wl;
    float a0 = 0.f, a1 = 0.f, a2 = 0.f, a3 = 0.f;
    const float* xn = x + n * 3 * 65536;
    for (int c = 0; c < 3; ++c) {
        const float* xc = xn + c * 65536;
        for (int ky = 0; ky < 5; ++ky) {
            int iy = oy * 2 - 2 + ky;
            if ((unsigned)iy >= 256u) continue;
            const float* xr = xc + iy * 256;
            for (int kx = 0; kx < 5; ++kx) {
                int ix = ox * 2 - 2 + kx;
                if ((unsigned)ix >= 256u) continue;
                float xv = xr[ix];
                float4 wq = wv[c * 25 + ky * 5 + kx];
                a0 += xv * wq.x; a1 += xv * wq.y; a2 += xv * wq.z; a3 += xv * wq.w;
            }
        }
    }
    int obase = ((n * 64 + oc0) * 128 + oy) * 128 + ox;
    z1[obase]         = gelu_exact(a0);
    z1[obase + 16384] = gelu_exact(a1);
    z1[obase + 32768] = gelu_exact(a2);
    z1[obase + 49152] = gelu_exact(a3);
}

// ---- conv2: [32,64,128,128] -> [32,64,64,64], k5 s2 p2, + gelu, fp32 ----
__global__ void conv2_k(const float* __restrict__ z1,
                        const float* __restrict__ w,   // [64,64,5,5]
                        float* __restrict__ z2) {
    __shared__ float wl[6400];                // [c*25+tap][j]
    const int oc0 = blockIdx.y * 4;
    for (int i = threadIdx.x; i < 6400; i += 256) {
        int j = i & 3, r = i >> 2;
        wl[i] = w[(oc0 + j) * 1600 + r];
    }
    __syncthreads();
    const int s = blockIdx.x * 256 + threadIdx.x;   // < 4096
    const int n = blockIdx.z;
    const int oy = s >> 6, ox = s & 63;
    const float4* wv = (const float4*)wl;
    float a0 = 0.f, a1 = 0.f, a2 = 0.f, a3 = 0.f;
    const float* zn = z1 + n * 64 * 16384;
    for (int c = 0; c < 64; ++c) {
        const float* zc = zn + c * 16384;
        for (int ky = 0; ky < 5; ++ky) {
            int iy = oy * 2 - 2 + ky;
            if ((unsigned)iy >= 128u) continue;
            const float* zr = zc + iy * 128;
            int rb = c * 25 + ky * 5;
            for (int kx = 0; kx < 5; ++kx) {
                int ix = ox * 2 - 2 + kx;
                if ((unsigned)ix >= 128u) continue;
                float xv = zr[ix];
                float4 wq = wv[rb + kx];
                a0 += xv * wq.x; a1 += xv * wq.y; a2 += xv * wq.z; a3 += xv * wq.w;
            }
        }
    }
    int obase = ((n * 64 + oc0) * 64 + oy) * 64 + ox;
    z2[obase]          = gelu_exact(a0);
    z2[obase + 4096]   = gelu_exact(a1);
    z2[obase + 8192]   = gelu_exact(a2);
    z2[obase + 12288]  = gelu_exact(a3);
}

// ---- conv3: [32,64,64,64] -> [32,64,63,63], k2 s1 p0, no act, fp32 ----
__global__ void conv3_k(const float* __restrict__ z2,
                        const float* __restrict__ w,   // [64,64,2,2]
                        float* __restrict__ z) {
    __shared__ float wl[1024];                // [c*4+tap][j]
    const int oc0 = blockIdx.y * 4;
    for (int i = threadIdx.x; i < 1024; i += 256) {
        int j = i & 3, r = i >> 2;
        wl[i] = w[(oc0 + j) * 256 + r];
    }
    __syncthreads();
    const int s = blockIdx.x * 256 + threadIdx.x;
    if (s >= 3969) return;
    const int n = blockIdx.z;
    const int oy = s / 63, ox = s % 63;
    const float4* wv = (const float4*)wl;
    float a0 = 0.f, a1 = 0.f, a2 = 0.f, a3 = 0.f;
    const float* zn = z2 + n * 64 * 4096;
    for (int c = 0; c < 64; ++c) {
        const float* zc = zn + c * 4096;
#pragma unroll
        for (int tap = 0; tap < 4; ++tap) {
            int iy = oy + (tap >> 1), ix = ox + (tap & 1);
            float xv = zc[iy * 64 + ix];
            float4 wq = wv[c * 4 + tap];
            a0 += xv * wq.x; a1 += xv * wq.y; a2 += xv * wq.z; a3 += xv * wq.w;
        }
    }
    int obase = (n * 64 + oc0) * 3969 + s;
    z[obase]            = a0;
    z[obase + 3969]     = a1;
    z[obase + 2 * 3969] = a2;
    z[obase + 3 * 3969] = a3;
}

// ---- VQ: argmin over 24 codes, z_probs out (fp32), commitment-loss sum ----
__global__ void vq_k(const float* __restrict__ z,          // [32,64,63,63]
                     const float* __restrict__ codes,      // [24,64]
                     const float* __restrict__ ema,        // [24]
                     int* __restrict__ idxO,
                     float* __restrict__ zprobsO,
                     float* __restrict__ lossO) {
    __shared__ float cl[1536];
    __shared__ float cn[24];
    __shared__ float pr[24];
    for (int i = threadIdx.x; i < 1536; i += 256) cl[i] = codes[i];
    if (threadIdx.x < 24) pr[threadIdx.x] = ema[threadIdx.x];
    __syncthreads();
    if (threadIdx.x < 24) {
        float sm = 0.f;
        for (int c = 0; c < 64; ++c) { float v = cl[threadIdx.x * 64 + c]; sm += v * v; }
        cn[threadIdx.x] = sm;
    }
    __syncthreads();
    int t = blockIdx.x * 256 + threadIdx.x;
    float l = 0.f;
    if (t < 127008) {
        int b = t / 3969, s = t - b * 3969;
        const float* zp = z + (b * 64) * 3969 + s;
        float zv[64];
        float zn = 0.f;
#pragma unroll
        for (int c = 0; c < 64; ++c) { float v = zp[c * 3969]; zv[c] = v; zn += v * v; }
        float best = 1e30f; int bi = 0;
        for (int k = 0; k < 24; ++k) {
            float dot = 0.f;
#pragma unroll
            for (int c = 0; c < 64; ++c) dot += zv[c] * cl[k * 64 + c];
            float d = zn - 2.f * dot + cn[k];
            if (d < best) { best = d; bi = k; }   // strict <: first-min, matches argmin
        }
        idxO[t] = bi;
        float psum = 0.f;
        for (int k = 0; k < 24; ++k) psum += pr[k];
        zprobsO[t] = pr[bi] / psum;
        for (int c = 0; c < 64; ++c) { float dd = cl[bi * 64 + c] - zv[c]; l += dd * dd; }
    }
    for (int off = 32; off; off >>= 1) l += __shfl_down(l, off, 64);
    if ((threadIdx.x & 63) == 0) atomicAdd(lossO, l);
}

// ---- D table: D[k][tap][oc] = sum_c codes[k][c] * dec_w1[oc][c][tap] ----
__global__ void dtab_k(const float* __restrict__ codes,
                       const float* __restrict__ w1,  // [512,64,2,2]
                       float* __restrict__ D) {
    int t = blockIdx.x * 256 + threadIdx.x;     // k*2048 + tap*512 + oc
    if (t >= 24 * 4 * 512) return;
    int oc = t & 511, tap = (t >> 9) & 3, k = t >> 11;
    float acc = 0.f;
    for (int c = 0; c < 64; ++c)
        acc += codes[k * 64 + c] * w1[oc * 256 + c * 4 + tap];
    D[t] = acc;
}

// ---- dec1 via D-table gather: -> y1 [32,512,64,64] bf16, + gelu ----
__global__ void dec1_k(const int* __restrict__ idx,            // [32,63,63]
                       const float* __restrict__ D,            // [24][4][512]
                       __hip_bfloat16* __restrict__ y1) {
    const int oc0 = blockIdx.y * 4;
    const int n = blockIdx.z;
    const int s = blockIdx.x * 256 + threadIdx.x;   // < 4096
    const int oy = s >> 6, ox = s & 63;
    float a0 = 0.f, a1 = 0.f, a2 = 0.f, a3 = 0.f;
    const int* idn = idx + n * 3969;
#pragma unroll
    for (int tap = 0; tap < 4; ++tap) {
        int iy = oy - 1 + (tap >> 1), ix = ox - 1 + (tap & 1);
        if ((unsigned)iy < 63u && (unsigned)ix < 63u) {
            int k = idn[iy * 63 + ix];
            float4 dv = *(const float4*)(D + (k * 4 + tap) * 512 + oc0);
            a0 += dv.x; a1 += dv.y; a2 += dv.z; a3 += dv.w;
        }
    }
    int obase = ((n * 512 + oc0) * 64 + oy) * 64 + ox;
    y1[obase]          = __float2bfloat16(gelu_exact(a0));
    y1[obase + 4096]   = __float2bfloat16(gelu_exact(a1));
    y1[obase + 8192]   = __float2bfloat16(gelu_exact(a2));
    y1[obase + 12288]  = __float2bfloat16(gelu_exact(a3));
}

// ---- dec2: [32,512,64,64] -> [32,256,63,63], k2 s1 p0, + gelu, bf16 ----
__global__ void dec2_k(const __hip_bfloat16* __restrict__ y1,
                       const float* __restrict__ w,   // [256,512,2,2]
                       __hip_bfloat16* __restrict__ y2) {
    __shared__ float wl[8192];                // [c*4+tap][j]
    const int oc0 = blockIdx.y * 4;
    for (int i = threadIdx.x; i < 8192; i += 256) {
        int j = i & 3, r = i >> 2;
        wl[i] = w[(oc0 + j) * 2048 + r];
    }
    __syncthreads();
    const int s = blockIdx.x * 256 + threadIdx.x;
    const int n = blockIdx.z;
    if (s >= 3969) return;
    const int oy = s / 63, ox = s % 63;
    const float4* wv = (const float4*)wl;
    float a0 = 0.f, a1 = 0.f, a2 = 0.f, a3 = 0.f;
    const __hip_bfloat16* yn = y1 + n * 512 * 4096;
    for (int c = 0; c < 512; ++c) {
        const __hip_bfloat16* yc = yn + c * 4096;
#pragma unroll
        for (int tap = 0; tap < 4; ++tap) {
            int iy = oy + (tap >> 1), ix = ox + (tap & 1);   // always in-bounds (in=64)
            float xv = __bfloat162float(yc[iy * 64 + ix]);
            float4 wq = wv[c * 4 + tap];
            a0 += xv * wq.x; a1 += xv * wq.y; a2 += xv * wq.z; a3 += xv * wq.w;
        }
    }
    int obase = (n * 256 + oc0) * 3969 + s;
    y2[obase]            = __float2bfloat16(gelu_exact(a0));
    y2[obase + 3969]     = __float2bfloat16(gelu_exact(a1));
    y2[obase + 2 * 3969] = __float2bfloat16(gelu_exact(a2));
    y2[obase + 3 * 3969] = __float2bfloat16(gelu_exact(a3));
}

// ---- dec3: [32,256,63,63] -> [32,256,64,64], k2 s1 p1, no act, fp32 out ----
__global__ void dec3_k(const __hip_bfloat16* __restrict__ y2,
                       const float* __restrict__ w,   // [256,256,2,2]
                       float* __restrict__ out) {
    __shared__ float wl[4096];                // [c*4+tap][j]
    const int oc0 = blockIdx.y * 4;
    for (int i = threadIdx.x; i < 4096; i += 256) {
        int j = i & 3, r = i >> 2;
        wl[i] = w[(oc0 + j) * 1024 + r];
    }
    __syncthreads();
    const int s = blockIdx.x * 256 + threadIdx.x;   // < 4096
    const int n = blockIdx.z;
    const int oy = s >> 6, ox = s & 63;
    const float4* wv = (const float4*)wl;
    float a0 = 0.f, a1 = 0.f, a2 = 0.f, a3 = 0.f;
    const __hip_bfloat16* yn = y2 + n * 256 * 3969;
    for (int c = 0; c < 256; ++c) {
        const __hip_bfloat16* yc = yn + c * 3969;
#pragma unroll
        for (int tap = 0; tap < 4; ++tap) {
            int iy = oy - 1 + (tap >> 1), ix = ox - 1 + (tap & 1);
            if ((unsigned)iy < 63u && (unsigned)ix < 63u) {
                float xv = __bfloat162float(yc[iy * 63 + ix]);
                float4 wq = wv[c * 4 + tap];
                a0 += xv * wq.x; a1 += xv * wq.y; a2 += xv * wq.z; a3 += xv * wq.w;
            }
        }
    }
    int obase = ((n * 256 + oc0) * 64 + oy) * 64 + ox;
    out[obase]         = a0;
    out[obase + 4096]  = a1;
    out[obase + 8192]  = a2;
    out[obase + 12288] = a3;
}

// ---- scalar: vq_loss = 0.25 * sum / (B*C*H*W) ----
__global__ void loss_k(const float* __restrict__ lossO, float* __restrict__ out) {
    out[0] = 0.25f * lossO[0] / 8128512.0f;
}

extern "C" void kernel_launch(void* const* d_in, const int* in_sizes, int n_in,
                              void* d_out, int out_size, void* d_ws, size_t ws_size,
                              hipStream_t stream) {
    const float* x     = (const float*)d_in[0];
    const float* ew1   = (const float*)d_in[1];
    const float* ew2   = (const float*)d_in[2];
    const float* ew3   = (const float*)d_in[3];
    const float* dw1   = (const float*)d_in[4];
    const float* dw2   = (const float*)d_in[5];
    const float* dw3   = (const float*)d_in[6];
    const float* codes = (const float*)d_in[7];
    const float* ema   = (const float*)d_in[8];
    float* out = (float*)d_out;

    // workspace layout (fp32 encoder intermediates; decoder reuses dead space)
    char* ws = (char*)d_ws;
    float* z1   = (float*)(ws + 0);            // 134,217,728 B [32,64,128,128] f32
    float* z2   = (float*)(ws + 134217728);    //  33,554,432 B [32,64,64,64]  f32
    float* z    = (float*)(ws + 167772160);    //  32,514,048 B [32,64,63,63]  f32
    int*   idx  = (int*)  (ws + 200286208);    //     508,032 B [32,63,63]     i32
    float* loss = (float*)(ws + 200794240);    //           4 B accumulator
    float* D    = (float*)(ws + 200794496);    //     786,432 B [24,4,512]     f32
    __hip_bfloat16* y1 = (__hip_bfloat16*)(ws + 0);          // reuse z1 region
    __hip_bfloat16* y2 = (__hip_bfloat16*)(ws + 134217728);  // reuse z2+z region

    hipMemsetAsync(loss, 0, 4, stream);

    conv1_k<<<dim3(64, 16, 32), 256, 0, stream>>>(x, ew1, z1);
    conv2_k<<<dim3(16, 16, 32), 256, 0, stream>>>(z1, ew2, z2);
    conv3_k<<<dim3(16, 16, 32), 256, 0, stream>>>(z2, ew3, z);
    vq_k<<<dim3(497), 256, 0, stream>>>(z, codes, ema, idx, out + 33554432, loss);
    dtab_k<<<dim3(192), 256, 0, stream>>>(codes, dw1, D);
    dec1_k<<<dim3(16, 128, 32), 256, 0, stream>>>(idx, D, y1);
    dec2_k<<<dim3(16, 64, 32), 256, 0, stream>>>(y1, dw2, y2);
    dec3_k<<<dim3(16, 64, 32), 256, 0, stream>>>(y2, dw3, out);
    loss_k<<<1, 1, 0, stream>>>(loss, out + 33681440);
}

// Round 3
// 2438.225 us; speedup vs baseline: 3.6070x; 3.6070x over previous
//
#include <hip/hip_runtime.h>
#include <hip/hip_bf16.h>

// ---------------------------------------------------------------------------
// BottleneckVQa. Encoder fp32 scalar (argmin stability), VQ, then MFMA bf16
// decoder: dec1 gather -> y1 NHWC bf16; dec2/dec3 as implicit-GEMM MFMA
// (m97 structure: 128x128 tile, BK=32, global_load_lds width-16 im2col).
// ---------------------------------------------------------------------------

#define DEV_INLINE __device__ __forceinline__

typedef __attribute__((ext_vector_type(8))) short bf16x8;
typedef __attribute__((ext_vector_type(4))) float f32x4;

#define GLL16(g, l) __builtin_amdgcn_global_load_lds(                      \
    (const __attribute__((address_space(1))) void*)(g),                    \
    (__attribute__((address_space(3))) void*)(l), 16, 0, 0)

DEV_INLINE float gelu_exact(float v) {
    return 0.5f * v * (1.0f + erff(v * 0.70710678118654752440f));
}

// ---- conv1: [32,3,256,256] -> [32,64,128,128], k5 s2 p2, + gelu, fp32 ----
__global__ void conv1_k(const float* __restrict__ x,
                        const float* __restrict__ w,   // [64,3,5,5]
                        float* __restrict__ z1) {
    __shared__ float wl[300];
    const int oc0 = blockIdx.y * 4;
    for (int i = threadIdx.x; i < 300; i += 256) {
        int j = i & 3, r = i >> 2;
        wl[i] = w[(oc0 + j) * 75 + r];
    }
    __syncthreads();
    const int s = blockIdx.x * 256 + threadIdx.x;
    const int n = blockIdx.z;
    const int oy = s >> 7, ox = s & 127;
    const float4* wv = (const float4*)wl;
    float a0 = 0.f, a1 = 0.f, a2 = 0.f, a3 = 0.f;
    const float* xn = x + n * 3 * 65536;
    for (int c = 0; c < 3; ++c) {
        const float* xc = xn + c * 65536;
        for (int ky = 0; ky < 5; ++ky) {
            int iy = oy * 2 - 2 + ky;
            if ((unsigned)iy >= 256u) continue;
            const float* xr = xc + iy * 256;
            for (int kx = 0; kx < 5; ++kx) {
                int ix = ox * 2 - 2 + kx;
                if ((unsigned)ix >= 256u) continue;
                float xv = xr[ix];
                float4 wq = wv[c * 25 + ky * 5 + kx];
                a0 += xv * wq.x; a1 += xv * wq.y; a2 += xv * wq.z; a3 += xv * wq.w;
            }
        }
    }
    int obase = ((n * 64 + oc0) * 128 + oy) * 128 + ox;
    z1[obase]         = gelu_exact(a0);
    z1[obase + 16384] = gelu_exact(a1);
    z1[obase + 32768] = gelu_exact(a2);
    z1[obase + 49152] = gelu_exact(a3);
}

// ---- conv2: [32,64,128,128] -> [32,64,64,64], k5 s2 p2, + gelu, fp32 ----
__global__ void conv2_k(const float* __restrict__ z1,
                        const float* __restrict__ w,   // [64,64,5,5]
                        float* __restrict__ z2) {
    __shared__ float wl[6400];
    const int oc0 = blockIdx.y * 4;
    for (int i = threadIdx.x; i < 6400; i += 256) {
        int j = i & 3, r = i >> 2;
        wl[i] = w[(oc0 + j) * 1600 + r];
    }
    __syncthreads();
    const int s = blockIdx.x * 256 + threadIdx.x;
    const int n = blockIdx.z;
    const int oy = s >> 6, ox = s & 63;
    const float4* wv = (const float4*)wl;
    float a0 = 0.f, a1 = 0.f, a2 = 0.f, a3 = 0.f;
    const float* zn = z1 + n * 64 * 16384;
    for (int c = 0; c < 64; ++c) {
        const float* zc = zn + c * 16384;
        for (int ky = 0; ky < 5; ++ky) {
            int iy = oy * 2 - 2 + ky;
            if ((unsigned)iy >= 128u) continue;
            const float* zr = zc + iy * 128;
            int rb = c * 25 + ky * 5;
            for (int kx = 0; kx < 5; ++kx) {
                int ix = ox * 2 - 2 + kx;
                if ((unsigned)ix >= 128u) continue;
                float xv = zr[ix];
                float4 wq = wv[rb + kx];
                a0 += xv * wq.x; a1 += xv * wq.y; a2 += xv * wq.z; a3 += xv * wq.w;
            }
        }
    }
    int obase = ((n * 64 + oc0) * 64 + oy) * 64 + ox;
    z2[obase]          = gelu_exact(a0);
    z2[obase + 4096]   = gelu_exact(a1);
    z2[obase + 8192]   = gelu_exact(a2);
    z2[obase + 12288]  = gelu_exact(a3);
}

// ---- conv3: [32,64,64,64] -> [32,64,63,63], k2 s1 p0, fp32 ----
__global__ void conv3_k(const float* __restrict__ z2,
                        const float* __restrict__ w,   // [64,64,2,2]
                        float* __restrict__ z) {
    __shared__ float wl[1024];
    const int oc0 = blockIdx.y * 4;
    for (int i = threadIdx.x; i < 1024; i += 256) {
        int j = i & 3, r = i >> 2;
        wl[i] = w[(oc0 + j) * 256 + r];
    }
    __syncthreads();
    const int s = blockIdx.x * 256 + threadIdx.x;
    if (s >= 3969) return;
    const int n = blockIdx.z;
    const int oy = s / 63, ox = s % 63;
    const float4* wv = (const float4*)wl;
    float a0 = 0.f, a1 = 0.f, a2 = 0.f, a3 = 0.f;
    const float* zn = z2 + n * 64 * 4096;
    for (int c = 0; c < 64; ++c) {
        const float* zc = zn + c * 4096;
#pragma unroll
        for (int tap = 0; tap < 4; ++tap) {
            int iy = oy + (tap >> 1), ix = ox + (tap & 1);
            float xv = zc[iy * 64 + ix];
            float4 wq = wv[c * 4 + tap];
            a0 += xv * wq.x; a1 += xv * wq.y; a2 += xv * wq.z; a3 += xv * wq.w;
        }
    }
    int obase = (n * 64 + oc0) * 3969 + s;
    z[obase]            = a0;
    z[obase + 3969]     = a1;
    z[obase + 2 * 3969] = a2;
    z[obase + 3 * 3969] = a3;
}

// ---- VQ: argmin over 24 codes, z_probs (fp32), commitment loss ----
__global__ void vq_k(const float* __restrict__ z,
                     const float* __restrict__ codes,
                     const float* __restrict__ ema,
                     int* __restrict__ idxO,
                     float* __restrict__ zprobsO,
                     float* __restrict__ lossO) {
    __shared__ float cl[1536];
    __shared__ float cn[24];
    __shared__ float pr[24];
    for (int i = threadIdx.x; i < 1536; i += 256) cl[i] = codes[i];
    if (threadIdx.x < 24) pr[threadIdx.x] = ema[threadIdx.x];
    __syncthreads();
    if (threadIdx.x < 24) {
        float sm = 0.f;
        for (int c = 0; c < 64; ++c) { float v = cl[threadIdx.x * 64 + c]; sm += v * v; }
        cn[threadIdx.x] = sm;
    }
    __syncthreads();
    int t = blockIdx.x * 256 + threadIdx.x;
    float l = 0.f;
    if (t < 127008) {
        int b = t / 3969, s = t - b * 3969;
        const float* zp = z + (b * 64) * 3969 + s;
        float zv[64];
        float zn = 0.f;
#pragma unroll
        for (int c = 0; c < 64; ++c) { float v = zp[c * 3969]; zv[c] = v; zn += v * v; }
        float best = 1e30f; int bi = 0;
        for (int k = 0; k < 24; ++k) {
            float dot = 0.f;
#pragma unroll
            for (int c = 0; c < 64; ++c) dot += zv[c] * cl[k * 64 + c];
            float d = zn - 2.f * dot + cn[k];
            if (d < best) { best = d; bi = k; }
        }
        idxO[t] = bi;
        float psum = 0.f;
        for (int k = 0; k < 24; ++k) psum += pr[k];
        zprobsO[t] = pr[bi] / psum;
        for (int c = 0; c < 64; ++c) { float dd = cl[bi * 64 + c] - zv[c]; l += dd * dd; }
    }
    for (int off = 32; off; off >>= 1) l += __shfl_down(l, off, 64);
    if ((threadIdx.x & 63) == 0) atomicAdd(lossO, l);
}

// ---- D table: D[k][tap][oc] = sum_c codes[k][c] * dec_w1[oc][c][tap] ----
__global__ void dtab_k(const float* __restrict__ codes,
                       const float* __restrict__ w1,  // [512,64,2,2]
                       float* __restrict__ D) {
    int t = blockIdx.x * 256 + threadIdx.x;
    if (t >= 24 * 4 * 512) return;
    int oc = t & 511, tap = (t >> 9) & 3, k = t >> 11;
    float acc = 0.f;
    for (int c = 0; c < 64; ++c)
        acc += codes[k * 64 + c] * w1[oc * 256 + c * 4 + tap];
    D[t] = acc;
}

// ---- weight transform: wT[oc][tap][c] bf16 from w[oc][c][2][2] fp32 ----
__global__ void wt_k(const float* __restrict__ w, __hip_bfloat16* __restrict__ wT,
                     int cl2, int total) {
    int t = blockIdx.x * 256 + threadIdx.x;
    if (t >= total) return;
    int c = t & ((1 << cl2) - 1);
    int tap = (t >> cl2) & 3;
    int oc = t >> (cl2 + 2);
    wT[t] = __float2bfloat16(w[((oc << cl2) + c) * 4 + tap]);
}

// ---- dec1: codebook gather -> y1 NHWC [32][64][64][512] bf16, + gelu ----
__global__ void dec1_k(const int* __restrict__ idx,   // [32,63,63]
                       const float* __restrict__ D,   // [24][4][512]
                       __hip_bfloat16* __restrict__ y1) {
    const int pos = blockIdx.x;                 // < 131072
    const int n = pos >> 12, rem = pos & 4095;
    const int iy = rem >> 6, ix = rem & 63;
    const int* idn = idx + n * 3969;
    const int t = threadIdx.x;                  // 2 oc per thread
    float ax = 0.f, ay = 0.f;
#pragma unroll
    for (int tap = 0; tap < 4; ++tap) {
        int py = iy - 1 + (tap >> 1), px = ix - 1 + (tap & 1);
        if ((unsigned)py < 63u && (unsigned)px < 63u) {
            int k = idn[py * 63 + px];
            float2 v = ((const float2*)(D + (k * 4 + tap) * 512))[t];
            ax += v.x; ay += v.y;
        }
    }
    __hip_bfloat162 o;
    o.x = __float2bfloat16(gelu_exact(ax));
    o.y = __float2bfloat16(gelu_exact(ay));
    ((__hip_bfloat162*)(y1 + (size_t)pos * 512))[t] = o;
}

// ---- dec2 MFMA: C[pos][oc] = sum_k y1im2col[pos][k] * wT2[oc][k] ----
// M=127008 pos, N=256 oc, K=2048 (tap*512+c). Output y2 NHWC bf16 + gelu.
__global__ __launch_bounds__(256) void dec2_mfma(
    const __hip_bfloat16* __restrict__ y1,   // NHWC [32][64][64][512]
    const __hip_bfloat16* __restrict__ wT,   // [256][2048]
    const __hip_bfloat16* __restrict__ zp,   // zero page (>=68KB zeros)
    __hip_bfloat16* __restrict__ y2)         // NHWC [32][63][63][256]
{
    __shared__ __hip_bfloat16 As[128 * 32];  // [pos][k] 8KB
    __shared__ __hip_bfloat16 Bs[128 * 32];  // [oc][k]  8KB
    const int tid = threadIdx.x;
    const int wave = tid >> 6, lane = tid & 63;
    const int quad = lane >> 4, l15 = lane & 15;
    const int m0 = blockIdx.x * 128;
    const int oc0 = blockIdx.y * 128;
    const int sub = tid & 3;

    const char* pA[2];
    const char* pB[2];
#pragma unroll
    for (int j = 0; j < 2; ++j) {
        int slot = j * 64 + (tid >> 2);
        int pp = m0 + slot;
        if (pp < 127008) {
            int n = pp / 3969; int r = pp - n * 3969;
            int oy = r / 63;  int ox = r - oy * 63;
            pA[j] = (const char*)y1 + (size_t)((n * 64 + oy) * 64 + ox) * 1024 + sub * 16;
        } else {
            pA[j] = (const char*)zp;   // zero page covers all tap/c offsets
        }
        pB[j] = (const char*)wT + (size_t)(oc0 + slot) * 4096 + sub * 16;
    }
    char* ldsA[2] = {(char*)As + wave * 1024, (char*)As + 4096 + wave * 1024};
    char* ldsB[2] = {(char*)Bs + wave * 1024, (char*)Bs + 4096 + wave * 1024};

    f32x4 acc[4][4] = {};
    const int wm = (wave & 1) * 64;   // over pos (M)
    const int wn = (wave >> 1) * 64;  // over oc  (N)

#pragma unroll
    for (int tap = 0; tap < 4; ++tap) {
        const int toff = ((tap >> 1) * 64 + (tap & 1)) * 1024;  // NHWC tap stride
        for (int kk = 0; kk < 16; ++kk) {
            const int cb = kk * 64;
            GLL16(pA[0] + toff + cb, ldsA[0]);
            GLL16(pA[1] + toff + cb, ldsA[1]);
            GLL16(pB[0] + tap * 1024 + cb, ldsB[0]);
            GLL16(pB[1] + tap * 1024 + cb, ldsB[1]);
            __syncthreads();
            bf16x8 af[4], bf[4];
#pragma unroll
            for (int mi = 0; mi < 4; ++mi)
                af[mi] = *(const bf16x8*)((const char*)As + (wm + mi * 16 + l15) * 64 + quad * 16);
#pragma unroll
            for (int ni = 0; ni < 4; ++ni)
                bf[ni] = *(const bf16x8*)((const char*)Bs + (wn + ni * 16 + l15) * 64 + quad * 16);
#pragma unroll
            for (int mi = 0; mi < 4; ++mi)
#pragma unroll
                for (int ni = 0; ni < 4; ++ni)
                    acc[mi][ni] = __builtin_amdgcn_mfma_f32_16x16x32_bf16(
                        af[mi], bf[ni], acc[mi][ni], 0, 0, 0);
            __syncthreads();
        }
    }
#pragma unroll
    for (int mi = 0; mi < 4; ++mi)
#pragma unroll
        for (int r = 0; r < 4; ++r) {
            int pos = m0 + wm + mi * 16 + quad * 4 + r;
            if (pos < 127008) {
#pragma unroll
                for (int ni = 0; ni < 4; ++ni) {
                    int oc = oc0 + wn + ni * 16 + l15;
                    y2[(size_t)pos * 256 + oc] =
                        __float2bfloat16(gelu_exact(acc[mi][ni][r]));
                }
            }
        }
}

// ---- dec3 MFMA: C[oc][pos] = sum_k wT3[oc][k] * y2im2col[pos][k] ----
// M=256 oc, N=131072 pos, K=1024 (tap*256+c). pad=1 via zero page. fp32 NCHW out.
__global__ __launch_bounds__(256) void dec3_mfma(
    const __hip_bfloat16* __restrict__ y2,   // NHWC [32][63][63][256]
    const __hip_bfloat16* __restrict__ wT,   // [256][1024]
    const __hip_bfloat16* __restrict__ zp,
    float* __restrict__ out)                 // NCHW [32][256][64][64]
{
    __shared__ __hip_bfloat16 As[128 * 32];  // weights [oc][k] 8KB
    __shared__ __hip_bfloat16 Bs[128 * 32];  // pos     [pos][k] 8KB
    const int tid = threadIdx.x;
    const int wave = tid >> 6, lane = tid & 63;
    const int quad = lane >> 4, l15 = lane & 15;
    const int p0 = blockIdx.x * 128;         // pos tile (N)
    const int oc0 = blockIdx.y * 128;        // oc tile (M)
    const int sub = tid & 3;

    const char* pW[2];
    const char* pP[4][2];
#pragma unroll
    for (int j = 0; j < 2; ++j) {
        int slot = j * 64 + (tid >> 2);
        pW[j] = (const char*)wT + (size_t)(oc0 + slot) * 2048 + sub * 16;
        int pp = p0 + slot;
        int n = pp >> 12, rem = pp & 4095;
        int OY = rem >> 6, OX = rem & 63;
#pragma unroll
        for (int tap = 0; tap < 4; ++tap) {
            int iy = OY - 1 + (tap >> 1), ix = OX - 1 + (tap & 1);
            if ((unsigned)iy < 63u && (unsigned)ix < 63u)
                pP[tap][j] = (const char*)y2 + (size_t)(n * 3969 + iy * 63 + ix) * 512 + sub * 16;
            else
                pP[tap][j] = (const char*)zp;
        }
    }
    char* ldsA[2] = {(char*)As + wave * 1024, (char*)As + 4096 + wave * 1024};
    char* ldsB[2] = {(char*)Bs + wave * 1024, (char*)Bs + 4096 + wave * 1024};

    f32x4 acc[4][4] = {};
    const int wm = (wave & 1) * 64;   // over oc  (M)
    const int wn = (wave >> 1) * 64;  // over pos (N)

#pragma unroll
    for (int tap = 0; tap < 4; ++tap) {
        for (int kk = 0; kk < 8; ++kk) {
            const int cb = kk * 64;
            GLL16(pW[0] + tap * 512 + cb, ldsA[0]);
            GLL16(pW[1] + tap * 512 + cb, ldsA[1]);
            GLL16(pP[tap][0] + cb, ldsB[0]);
            GLL16(pP[tap][1] + cb, ldsB[1]);
            __syncthreads();
            bf16x8 af[4], bf[4];
#pragma unroll
            for (int mi = 0; mi < 4; ++mi)
                af[mi] = *(const bf16x8*)((const char*)As + (wm + mi * 16 + l15) * 64 + quad * 16);
#pragma unroll
            for (int ni = 0; ni < 4; ++ni)
                bf[ni] = *(const bf16x8*)((const char*)Bs + (wn + ni * 16 + l15) * 64 + quad * 16);
#pragma unroll
            for (int mi = 0; mi < 4; ++mi)
#pragma unroll
                for (int ni = 0; ni < 4; ++ni)
                    acc[mi][ni] = __builtin_amdgcn_mfma_f32_16x16x32_bf16(
                        af[mi], bf[ni], acc[mi][ni], 0, 0, 0);
            __syncthreads();
        }
    }
    const int n = p0 >> 12;
    const int posLocal0 = (p0 & 4095) + wn;
#pragma unroll
    for (int mi = 0; mi < 4; ++mi)
#pragma unroll
        for (int r = 0; r < 4; ++r) {
            int oc = oc0 + wm + mi * 16 + quad * 4 + r;
            float* orow = out + ((size_t)(n * 256 + oc) << 12);
#pragma unroll
            for (int ni = 0; ni < 4; ++ni)
                orow[posLocal0 + ni * 16 + l15] = acc[mi][ni][r];
        }
}

// ---- scalar: vq_loss = 0.25 * sum / (B*C*H*W) ----
__global__ void loss_k(const float* __restrict__ lossO, float* __restrict__ out) {
    out[0] = 0.25f * lossO[0] / 8128512.0f;
}

extern "C" void kernel_launch(void* const* d_in, const int* in_sizes, int n_in,
                              void* d_out, int out_size, void* d_ws, size_t ws_size,
                              hipStream_t stream) {
    const float* x     = (const float*)d_in[0];
    const float* ew1   = (const float*)d_in[1];
    const float* ew2   = (const float*)d_in[2];
    const float* ew3   = (const float*)d_in[3];
    const float* dw1   = (const float*)d_in[4];
    const float* dw2   = (const float*)d_in[5];
    const float* dw3   = (const float*)d_in[6];
    const float* codes = (const float*)d_in[7];
    const float* ema   = (const float*)d_in[8];
    float* out = (float*)d_out;

    char* ws = (char*)d_ws;
    float* z1   = (float*)(ws + 0);            // 134,217,728 B [32,64,128,128] f32
    float* z2   = (float*)(ws + 134217728);    //  33,554,432 B [32,64,64,64]  f32
    float* z    = (float*)(ws + 167772160);    //  32,514,048 B [32,64,63,63]  f32
    int*   idx  = (int*)  (ws + 200286208);    //     508,032 B [32,63,63]     i32
    float* loss = (float*)(ws + 200794240);    //         256 B accumulator
    __hip_bfloat16* zp  = (__hip_bfloat16*)(ws + 200794496);  // 69,632 B zero page
    float* D    = (float*)(ws + 200864128);    //     786,432 B [24,4,512]     f32
    __hip_bfloat16* wT2 = (__hip_bfloat16*)(ws + 201650560);  // 1,048,576 B [256][2048]
    __hip_bfloat16* wT3 = (__hip_bfloat16*)(ws + 202699136);  //   524,288 B [256][1024]
    __hip_bfloat16* y1  = (__hip_bfloat16*)(ws + 0);          // reuse z1: 134,217,728 B
    __hip_bfloat16* y2  = (__hip_bfloat16*)(ws + 134217728);  // reuse z2+z: 65,028,096 B

    hipMemsetAsync(loss, 0, 4, stream);
    hipMemsetAsync(zp, 0, 69632, stream);

    conv1_k<<<dim3(64, 16, 32), 256, 0, stream>>>(x, ew1, z1);
    conv2_k<<<dim3(16, 16, 32), 256, 0, stream>>>(z1, ew2, z2);
    conv3_k<<<dim3(16, 16, 32), 256, 0, stream>>>(z2, ew3, z);
    vq_k<<<dim3(497), 256, 0, stream>>>(z, codes, ema, idx, out + 33554432, loss);
    dtab_k<<<dim3(192), 256, 0, stream>>>(codes, dw1, D);
    wt_k<<<dim3(2048), 256, 0, stream>>>(dw2, wT2, 9, 524288);   // C=512
    wt_k<<<dim3(1024), 256, 0, stream>>>(dw3, wT3, 8, 262144);   // C=256
    dec1_k<<<dim3(131072), 256, 0, stream>>>(idx, D, y1);
    dec2_mfma<<<dim3(993, 2), 256, 0, stream>>>(y1, wT2, zp, y2);
    dec3_mfma<<<dim3(1024, 2), 256, 0, stream>>>(y2, wT3, zp, out);
    loss_k<<<1, 1, 0, stream>>>(loss, out + 33681440);
}